// Round 1
// baseline (227.299 us; speedup 1.0000x reference)
//
#include <hip/hip_runtime.h>

// Gated SPN, reverse scan over W.
// h(i,t) = a*x + g1*h(i-1,t+1) + g2*h(i,t+1) + g3*h(i+1,t+1),  a = 1-g1-g2-g3
// gates pre-normalized so |g1|+|g2|+|g3| <= 1 when it exceeded 1.
//
// Decomposition: 1 block per (b,c) slice (128 blocks), 512 threads = 1/row.
// W processed right-to-left in tiles of WT=16 columns staged through LDS in a
// transposed float4 layout {a*x, g1n, g2n, g3n} so the inner step loop does a
// single conflict-free ds_read_b128 per thread. h neighbor exchange via a
// double-buffered (H+2) LDS line with zero boundaries, 1 barrier/step.

#define HH 512
#define WW 512
#define WT 16
#define NTILES (WW / WT)
#define NT 512   // threads per block (1 per H row)

// normalize one element and store {a*x, g1, g2, g3} into the transposed tile
#define NORM_STORE(xx, g1v, g2v, g3v, wl, rr)                                  \
    {                                                                          \
        float sa_ = fabsf(g1v) + fabsf(g2v) + fabsf(g3v);                      \
        float sc_ = (sa_ >= 1.0f) ? (1.0f / sa_) : 1.0f;                       \
        float n1_ = (g1v) * sc_, n2_ = (g2v) * sc_, n3_ = (g3v) * sc_;         \
        float aa_ = 1.0f - n1_ - n2_ - n3_;                                    \
        tile[(wl) * HH + (rr)] = make_float4(aa_ * (xx), n1_, n2_, n3_);       \
    }

__global__ __launch_bounds__(NT) void spn_kernel(
    const float* __restrict__ X, const float* __restrict__ G1,
    const float* __restrict__ G2, const float* __restrict__ G3,
    float* __restrict__ OUT)
{
    extern __shared__ char smem[];
    float4* tile = (float4*)smem;                              // [WT][HH] of {ax,g1,g2,g3}
    float*  hb   = (float*)(smem + (size_t)WT * HH * sizeof(float4)); // [2][HH+2]
    float* hP = hb;             // holds h at step t+1 when a step begins
    float* hQ = hb + (HH + 2);

    const int tid = threadIdx.x;
    const size_t base = (size_t)blockIdx.x * (size_t)(HH * WW);
    const float* Xp  = X  + base;
    const float* G1p = G1 + base;
    const float* G2p = G2 + base;
    const float* G3p = G3 + base;
    float* Op = OUT + base;

    // init h state (zeros at w = W), boundaries of both buffers stay 0 forever
    hP[tid + 1] = 0.0f;
    if (tid == 0) { hP[0] = 0.0f; hP[HH + 1] = 0.0f; hQ[0] = 0.0f; hQ[HH + 1] = 0.0f; }

    // load geometry: 4 lanes cover one row's 64B (16 floats); 4 rounds cover 512 rows
    const int lrow0 = tid >> 2;   // row for round j is lrow0 + j*128
    const int lq    = tid & 3;    // 16B quarter within the row

    float4 rx[4], r1[4], r2[4], r3[4];   // staging regs (statically indexed)

    // prologue: load tile 0 (rightmost)
    {
        const int w0 = WW - WT;
        #pragma unroll
        for (int j = 0; j < 4; ++j) {
            const size_t off = (size_t)(lrow0 + j * 128) * WW + (size_t)(w0 + lq * 4);
            rx[j] = *(const float4*)(Xp  + off);
            r1[j] = *(const float4*)(G1p + off);
            r2[j] = *(const float4*)(G2p + off);
            r3[j] = *(const float4*)(G3p + off);
        }
    }

    __syncthreads();   // hbuf init visible

    float h = 0.0f;    // this thread's h at step t+1

    for (int t = 0; t < NTILES; ++t) {
        const int w0 = WW - WT * (t + 1);

        // ---- stage: normalize regs -> transposed LDS tile ----
        #pragma unroll
        for (int j = 0; j < 4; ++j) {
            const int r  = lrow0 + j * 128;
            const int wb = lq * 4;
            NORM_STORE(rx[j].x, r1[j].x, r2[j].x, r3[j].x, wb + 0, r);
            NORM_STORE(rx[j].y, r1[j].y, r2[j].y, r3[j].y, wb + 1, r);
            NORM_STORE(rx[j].z, r1[j].z, r2[j].z, r3[j].z, wb + 2, r);
            NORM_STORE(rx[j].w, r1[j].w, r2[j].w, r3[j].w, wb + 3, r);
        }

        // ---- issue next tile's global loads (fly during compute) ----
        if (t + 1 < NTILES) {
            const int w0n = w0 - WT;
            #pragma unroll
            for (int j = 0; j < 4; ++j) {
                const size_t off = (size_t)(lrow0 + j * 128) * WW + (size_t)(w0n + lq * 4);
                rx[j] = *(const float4*)(Xp  + off);
                r1[j] = *(const float4*)(G1p + off);
                r2[j] = *(const float4*)(G2p + off);
                r3[j] = *(const float4*)(G3p + off);
            }
        }

        __syncthreads();   // tile visible

        // ---- compute WT steps, w = w0+WT-1 ... w0 ----
        float hout[WT];
        #pragma unroll
        for (int s = 0; s < WT; ++s) {
            const int q = WT - 1 - s;
            const float* hr = (s & 1) ? hQ : hP;   // compile-time after unroll
            float*       hw = (s & 1) ? hP : hQ;
            const float4 v = tile[q * HH + tid];   // {ax, g1, g2, g3}
            const float hu = hr[tid];              // h(i-1, t+1)
            const float hd = hr[tid + 2];          // h(i+1, t+1)
            const float hn = fmaf(v.y, hu, fmaf(v.z, h, fmaf(v.w, hd, v.x)));
            hw[tid + 1] = hn;
            h = hn;
            hout[q] = hn;
            __syncthreads();
        }

        // ---- write this tile's outputs (own row, 2x16B... 4x16B contiguous 64B) ----
        #pragma unroll
        for (int j = 0; j < 4; ++j) {
            const float4 o = make_float4(hout[j * 4 + 0], hout[j * 4 + 1],
                                         hout[j * 4 + 2], hout[j * 4 + 3]);
            *(float4*)(Op + (size_t)tid * WW + (size_t)(w0 + j * 4)) = o;
        }
        // no extra barrier: last step's __syncthreads covers the tile reuse
    }
}

extern "C" void kernel_launch(void* const* d_in, const int* in_sizes, int n_in,
                              void* d_out, int out_size, void* d_ws, size_t ws_size,
                              hipStream_t stream) {
    const float* X  = (const float*)d_in[0];
    const float* G1 = (const float*)d_in[1];
    const float* G2 = (const float*)d_in[2];
    const float* G3 = (const float*)d_in[3];
    float* OUT = (float*)d_out;

    const int nblocks = 4 * 32;  // B*C slices
    const size_t smem = (size_t)WT * HH * sizeof(float4) + 2 * (HH + 2) * sizeof(float);

    // opt in to >64KB dynamic LDS (gfx950 allows up to 160KB/workgroup)
    (void)hipFuncSetAttribute((const void*)spn_kernel,
                              hipFuncAttributeMaxDynamicSharedMemorySize, (int)smem);

    spn_kernel<<<nblocks, NT, smem, stream>>>(X, G1, G2, G3, OUT);
}